// Round 16
// baseline (537.827 us; speedup 1.0000x reference)
//
#include <hip/hip_runtime.h>
#include <hip/hip_bf16.h>
#include <math.h>

using bf16 = __hip_bfloat16;
typedef __bf16 bf16x8 __attribute__((ext_vector_type(8)));
typedef float f32x4 __attribute__((ext_vector_type(4)));
typedef unsigned short us8 __attribute__((ext_vector_type(8)));

#define EPS16F 0.0009765625f

__device__ __forceinline__ float b2f(bf16 v){ return __bfloat162float(v); }
__device__ __forceinline__ bf16  f2b(float f){ return __float2bfloat16(f); }
__device__ __forceinline__ unsigned short f2bu(float f){
  bf16 h = __float2bfloat16(f); return __builtin_bit_cast(unsigned short, h);
}
__device__ __forceinline__ float u2f(unsigned short u){
  return b2f(__builtin_bit_cast(bf16, u));
}

__device__ __forceinline__ void gload16(const void* g, void* l){
  __builtin_amdgcn_global_load_lds((const __attribute__((address_space(1))) void*)g,
                                   (__attribute__((address_space(3))) void*)l, 16, 0, 0);
}

typedef const __attribute__((address_space(3))) char* lds_cp;

// LDS vector read with compile-time immediate offset (must be < 65536)
template<unsigned OFF>
__device__ __forceinline__ bf16x8 dsr(lds_cp p){
  static_assert(OFF < 65536u, "ds_read offset is 16-bit");
  bf16x8 d;
  asm volatile("ds_read_b128 %0, %1 offset:%c2"
               : "=v"(d) : "v"(p), "i"(OFF));
  return d;
}

// ---------------- fused fp32 -> bf16 convert for all 4 weights ----------------
__global__ void k_f2b_all(const float* __restrict__ w0, const float* __restrict__ w1,
                          const float* __restrict__ w2, const float* __restrict__ w3,
                          bf16* __restrict__ o0, bf16* __restrict__ o1,
                          bf16* __restrict__ o2, bf16* __restrict__ o3){
  // segments (elements): 1M, 1M, 4M, 4M
  long long i = (long long)(blockIdx.x*blockDim.x + threadIdx.x)*4;
  const float* in; bf16* out; long long off;
  if (i < 1048576){ in = w0; out = o0; off = i; }
  else if (i < 2097152){ in = w1; out = o1; off = i - 1048576; }
  else if (i < 6291456){ in = w2; out = o2; off = i - 2097152; }
  else { in = w3; out = o3; off = i - 6291456; }
  float4 v = *(const float4*)(in + off);
  ushort4 pk = make_ushort4(f2bu(v.x), f2bu(v.y), f2bu(v.z), f2bu(v.w));
  *reinterpret_cast<ushort4*>(out + off) = pk;
}

// ---------------- LN1 stats phase 1 ----------------
__global__ void __launch_bounds__(256) k_ln1_part(const float* __restrict__ x,
                                                  float* __restrict__ Ps,
                                                  float* __restrict__ Pq){
  int chunk = blockIdx.x, b = blockIdx.y;
  int t = threadIdx.x;
  const float4* xp = (const float4*)(x + ((size_t)b*1024 + chunk*16)*1024) + t;
  float4 s = {0.f,0.f,0.f,0.f}, q = {0.f,0.f,0.f,0.f};
  #pragma unroll
  for (int c = 0; c < 16; ++c){
    float4 v = xp[c*256];
    s.x += v.x; s.y += v.y; s.z += v.z; s.w += v.w;
    q.x += v.x*v.x; q.y += v.y*v.y; q.z += v.z*v.z; q.w += v.w*v.w;
  }
  size_t o = ((size_t)(b*64 + chunk))*256 + t;
  ((float4*)Ps)[o] = s;
  ((float4*)Pq)[o] = q;
}

// ---------------- LN1 stats phase 2 ----------------
__global__ void __launch_bounds__(256) k_ln1_finish(const float* __restrict__ Ps,
                                                    const float* __restrict__ Pq,
                                                    float* __restrict__ mu,
                                                    float* __restrict__ rs){
  int nb = blockIdx.x, b = blockIdx.y;
  int n = nb*256 + threadIdx.x;
  const float* ps = Ps + (size_t)b*64*1024 + n;
  const float* pq = Pq + (size_t)b*64*1024 + n;
  float S = 0.f, Q = 0.f;
  #pragma unroll 8
  for (int c = 0; c < 64; ++c){ S += ps[(size_t)c*1024]; Q += pq[(size_t)c*1024]; }
  float m = S*(1.f/1024.f);
  float var = Q*(1.f/1024.f) - m*m;
  mu[b*1024 + n] = m;
  rs[b*1024 + n] = rsqrtf(var + 1e-5f);
}

// ---------------- LN1 apply + transpose ----------------
__global__ void k_ln1_apply(const float* __restrict__ x, const float* __restrict__ mu,
                            const float* __restrict__ rs, const float* __restrict__ w,
                            const float* __restrict__ bias, bf16* __restrict__ y3){
  int b = blockIdx.z, c0 = blockIdx.y*64, n0 = blockIdx.x*64;
  __shared__ float t[64][65];
  int j = threadIdx.x & 63, i0 = (threadIdx.x >> 6)*16;
  const float* xp = x + ((size_t)b*1024 + c0)*1024 + n0;
  #pragma unroll
  for (int r = 0; r < 16; ++r)
    t[j][i0 + r] = xp[(size_t)(i0 + r)*1024 + j];
  __syncthreads();
  int i = threadIdx.x & 63, jj0 = (threadIdx.x >> 6)*16;
  float wc = w[c0 + i], bc = bias[c0 + i];
  bf16* yp = y3 + ((size_t)b*1024 + n0)*1024 + c0 + i;
  #pragma unroll
  for (int r = 0; r < 16; ++r){
    int n = n0 + jj0 + r;
    float v = t[jj0 + r][i];
    yp[(size_t)(jj0 + r)*1024] = f2b((v - mu[b*1024 + n])*rs[b*1024 + n]*wc + bc);
  }
}

// ================= 256x256 8-phase GEMM (R7 best-measured) =================
// EPI: 0 plain, 1 +bias+fast-gelu, 3 +bias+accumulate-into-out,
//      4 +bias, then v = xres[idx] + aux[col]*v  (fused residual-2 add)
#define PH(PA, PB, JO, MH, VM, STAGE_STMT)                                     \
  {                                                                            \
    if ((MH) == 0){                                                            \
      b[0] = dsr<(JO) +    0>(PB); b[1] = dsr<(JO) + 1024>(PB);                \
      b[2] = dsr<(JO) + 2048>(PB); b[3] = dsr<(JO) + 3072>(PB);                \
    }                                                                          \
    a[0] = dsr<(JO) + (MH)*4096u +    0>(PA);                                  \
    a[1] = dsr<(JO) + (MH)*4096u + 1024>(PA);                                  \
    a[2] = dsr<(JO) + (MH)*4096u + 2048>(PA);                                  \
    a[3] = dsr<(JO) + (MH)*4096u + 3072>(PA);                                  \
    STAGE_STMT;                                                                \
    if (VM) asm volatile("s_waitcnt vmcnt(4)" ::: "memory");                   \
    __builtin_amdgcn_s_barrier();                                              \
    asm volatile("s_waitcnt lgkmcnt(0)" ::: "memory");                         \
    __builtin_amdgcn_sched_barrier(0);                                         \
    __builtin_amdgcn_s_setprio(1);                                             \
    _Pragma("unroll")                                                          \
    for (int i_ = 0; i_ < 4; ++i_)                                             \
      _Pragma("unroll")                                                        \
      for (int n_ = 0; n_ < 4; ++n_)                                           \
        acc[(MH)*4 + i_][n_] = __builtin_amdgcn_mfma_f32_16x16x32_bf16(        \
            a[i_], b[n_], acc[(MH)*4 + i_][n_], 0, 0, 0);                      \
    __builtin_amdgcn_s_setprio(0);                                             \
    __builtin_amdgcn_s_barrier();                                              \
  }

#define STAGE_A(KB, SLOT)                                                      \
  { const char* g_ = Ag + (size_t)(KB)*2;                                      \
    gload16(g_,        smem + (SLOT)*32768 + t*16);                            \
    gload16(g_ + a128, smem + (SLOT)*32768 + 8192 + t*16); }
#define STAGE_B(KB, SLOT)                                                      \
  { const char* g_ = Wg + (size_t)(KB)*2;                                      \
    gload16(g_,        smem + (SLOT)*32768 + 16384 + t*16);                    \
    gload16(g_ + w128, smem + (SLOT)*32768 + 16384 + 8192 + t*16); }

template<int EPI>
__global__ void __launch_bounds__(512, 2) k_gemm8(const bf16* __restrict__ A,
                                                  const bf16* __restrict__ W,
                                                  bf16* __restrict__ out,
                                                  const float* __restrict__ bias,
                                                  const bf16* __restrict__ xres,
                                                  const float* __restrict__ aux,
                                                  int K, int lda, int ldw, int ldo,
                                                  int nbx){
  __shared__ __align__(16) char smem[131072];
  int nwg = gridDim.x;
  int cpx = nwg >> 3;
  int bid = blockIdx.x;
  int swz = (bid & 7)*cpx + (bid >> 3);
  int bx = swz % nbx, by = swz / nbx;
  int m0 = by*256, n0 = bx*256;
  int t = threadIdx.x;
  int lane = t & 63, wave = t >> 6;
  int wr = wave >> 2, wc = wave & 3;     // 2x4 waves; each owns 128x64
  int lr = lane & 15, lg = lane >> 4;
  unsigned cswz = (unsigned)((lg ^ ((lr >> 1) & 3))*16);
  int srow = t >> 2;
  int sg = (t & 3) ^ ((t >> 3) & 3);
  f32x4 acc[8][4] = {};
  bf16x8 a[4], b[4];
  int nt = K >> 6;                        // even (K = 1024/2048/4096)

  const char* Ag = (const char*)A + ((size_t)(m0 + srow)*lda + sg*8)*2;
  const char* Wg = (const char*)W + ((size_t)(n0 + srow)*ldw + sg*8)*2;
  const size_t a128 = (size_t)lda*256;    // +128 rows, bytes
  const size_t w128 = (size_t)ldw*256;
  lds_cp pa0 = (lds_cp)(smem + (wr*128 + lr)*64 + cswz);
  lds_cp pb0 = (lds_cp)(smem + 16384 + (wc*64 + lr)*64 + cswz);
  lds_cp pa1 = pa0 + 65536;
  lds_cp pb1 = pb0 + 65536;

  STAGE_A(0, 0)  STAGE_B(0, 0)
  STAGE_A(32, 1) STAGE_B(32, 1)
  asm volatile("s_waitcnt vmcnt(4)" ::: "memory");
  __builtin_amdgcn_s_barrier();

  int nh = nt >> 1;
  for (int tp = 0; tp < nh; ++tp){
    int tt = tp*2;
    int kn  = (tt + 1)*64;
    int kn2 = (tt + 2 < nt) ? (tt + 2)*64 : 0;
    PH(pa0, pb0, 0u,     0, 0, STAGE_A(kn, 2))
    PH(pa0, pb0, 0u,     1, 1, STAGE_B(kn, 2))
    PH(pa0, pb0, 32768u, 0, 0, STAGE_A(kn + 32, 3))
    PH(pa0, pb0, 32768u, 1, 1, STAGE_B(kn + 32, 3))
    PH(pa1, pb1, 0u,     0, 0, STAGE_A(kn2, 0))
    PH(pa1, pb1, 0u,     1, 1, STAGE_B(kn2, 0))
    PH(pa1, pb1, 32768u, 0, 0, STAGE_A(kn2 + 32, 1))
    PH(pa1, pb1, 32768u, 1, 1, STAGE_B(kn2 + 32, 1))
  }

  #pragma unroll
  for (int m = 0; m < 8; ++m){
    #pragma unroll
    for (int n = 0; n < 4; ++n){
      int col = n0 + wc*64 + n*16 + lr;
      #pragma unroll
      for (int j = 0; j < 4; ++j){
        int row = m0 + wr*128 + m*16 + lg*4 + j;
        size_t idx = (size_t)row*ldo + col;
        float v = acc[m][n][j];
        if (EPI >= 1) v += bias[col];
        if (EPI == 1) v = v / (1.f + __expf(-1.702f*v));   // fast gelu
        if (EPI == 3) v += b2f(out[idx]);
        if (EPI == 4) v = b2f(xres[idx]) + aux[col]*v;     // fused resid2 add
        out[idx] = f2b(v);
      }
    }
  }
}

// ---------- TSSA chain: vectorized (bf16x8 staged) versions ----------
template<bool WEIGHTED>
__global__ void __launch_bounds__(128) k_chunksum(const bf16* __restrict__ Wb,
                                                  const float* __restrict__ Pi,
                                                  float* __restrict__ S){
  int blk = blockIdx.x;
  int ch = blk & 15, h = (blk >> 4) & 7, b = blk >> 7;
  int t = threadIdx.x;
  int nl = t >> 4, d8 = (t & 15)*8;
  const bf16* gb = Wb + ((size_t)(b*1024 + ch*64))*1024 + h*128 + d8;
  const float* pip = Pi + (size_t)(b*8 + h)*1024 + ch*64;
  float acc[8] = {};
  #pragma unroll
  for (int p = 0; p < 8; ++p){
    int n = p*8 + nl;
    us8 v = *(const us8*)(gb + (size_t)n*1024);
    float pi = WEIGHTED ? pip[n] : 1.f;
    #pragma unroll
    for (int j = 0; j < 8; ++j){
      float w = u2f(v[j]);
      acc[j] += w*w*pi;
    }
  }
  __shared__ float Sp[8][128];
  #pragma unroll
  for (int j = 0; j < 8; ++j) Sp[nl][d8 + j] = acc[j];
  __syncthreads();
  float s = 0.f;
  #pragma unroll
  for (int g = 0; g < 8; ++g) s += Sp[g][t];
  S[(size_t)blk*128 + t] = s;
}

__global__ void __launch_bounds__(128) k_stageA(const bf16* __restrict__ Wb,
                                                const float* __restrict__ S1,
                                                const float* __restrict__ temp,
                                                const float* __restrict__ dbias,
                                                float* __restrict__ tmp){
  int blk = blockIdx.x;
  int ch = blk & 15, h = (blk >> 4) & 7, b = blk >> 7;
  int t = threadIdx.x;
  __shared__ __align__(16) unsigned short Wl[64][136];
  __shared__ float V[64][129];
  int nl = t >> 4, d8 = (t & 15)*8;
  const bf16* gb = Wb + ((size_t)(b*1024 + ch*64))*1024 + h*128 + d8;
  #pragma unroll
  for (int p = 0; p < 8; ++p){
    int n = p*8 + nl;
    *(us8*)&Wl[n][d8] = *(const us8*)(gb + (size_t)n*1024);
  }
  const float* sp = S1 + (size_t)(b*8 + h)*16*128 + t;
  float base = 0.f;
  for (int c = 0; c < ch; ++c) base += sp[(size_t)c*128];
  __syncthreads();
  float run = base;                        // t = d
  for (int n = 0; n < 64; ++n){
    float w = u2f(Wl[n][t]);
    float sq = w*w;
    run += sq;
    V[n][t] = sq / fmaxf(run, EPS16F);
  }
  __syncthreads();
  int n_loc = t >> 1, half = t & 1;
  float s = 0.f;
  for (int k = 0; k < 64; ++k) s += V[n_loc][half*64 + k];
  s += __shfl_xor(s, 1);
  if (half == 0){
    int n = ch*64 + n_loc;
    float db = dbias[h*1024 + n];
    tmp[(size_t)(b*8 + h)*1024 + n] = (s + 128.f*db)*temp[h];
  }
}

__global__ void k_softmax_scan(const float* __restrict__ tmp, float* __restrict__ Pi,
                               float* __restrict__ Pc){
  int bh = blockIdx.x; int b = bh >> 3, h = bh & 7;
  int t = threadIdx.x;
  const float* tp = tmp + (size_t)b*8*1024;
  float p[4];
  #pragma unroll
  for (int i = 0; i < 4; ++i){
    int n = t*4 + i;
    float v[8]; float mx = -1e30f;
    #pragma unroll
    for (int hh = 0; hh < 8; ++hh){ v[hh] = tp[hh*1024 + n]; mx = fmaxf(mx, v[hh]); }
    float Z = 0.f;
    #pragma unroll
    for (int hh = 0; hh < 8; ++hh) Z += expf(v[hh] - mx);
    p[i] = expf(v[h] - mx)/Z;
    Pi[(size_t)bh*1024 + n] = p[i];
  }
  float l0 = p[0], l1 = l0 + p[1], l2 = l1 + p[2], l3 = l2 + p[3];
  float ts = l3, sc = ts;
  int ln = t & 63, wv = t >> 6;
  #pragma unroll
  for (int d = 1; d < 64; d <<= 1){
    float o = __shfl_up(sc, d);
    if (ln >= d) sc += o;
  }
  __shared__ float wsum[4];
  if (ln == 63) wsum[wv] = sc;
  __syncthreads();
  float woff = 0.f;
  for (int w2 = 0; w2 < 4; ++w2) if (w2 < wv) woff += wsum[w2];
  float excl = woff + sc - ts;
  size_t o4 = (size_t)bh*1024 + t*4;
  Pc[o4]   = excl + l0;
  Pc[o4+1] = excl + l1;
  Pc[o4+2] = excl + l2;
  Pc[o4+3] = excl + l3;
}

__global__ void __launch_bounds__(128) k_stageC(const bf16* __restrict__ Wb,
                                                const float* __restrict__ S2,
                                                const float* __restrict__ Pi,
                                                const float* __restrict__ Pc,
                                                bf16* __restrict__ Y){
  int blk = blockIdx.x;
  int ch = blk & 15, h = (blk >> 4) & 7, b = blk >> 7;
  int t = threadIdx.x;
  __shared__ __align__(16) unsigned short Wl[64][136];
  int nl = t >> 4, d8 = (t & 15)*8;
  const bf16* gb = Wb + ((size_t)(b*1024 + ch*64))*1024 + h*128 + d8;
  #pragma unroll
  for (int p = 0; p < 8; ++p){
    int n = p*8 + nl;
    *(us8*)&Wl[n][d8] = *(const us8*)(gb + (size_t)n*1024);
  }
  const float* sp = S2 + (size_t)(b*8 + h)*16*128 + t;
  float base = 0.f;
  for (int c = 0; c < ch; ++c) base += sp[(size_t)c*128];
  const float* pip = Pi + (size_t)(b*8 + h)*1024 + ch*64;
  const float* pcp = Pc + (size_t)(b*8 + h)*1024 + ch*64;
  __syncthreads();
  float run = base;                        // t = d
  for (int n = 0; n < 64; ++n){
    float w = u2f(Wl[n][t]);
    float sq = w*w;
    float pi = pip[n];
    run += sq*pi;
    float dots = run / (pcp[n] + EPS16F);
    float at = 1.0f/(1.0f + dots);
    Wl[n][t] = f2bu(-(w*pi)*at);           // column-exclusive overwrite
  }
  __syncthreads();
  bf16* yb = Y + ((size_t)(b*1024 + ch*64))*1024 + h*128 + d8;
  #pragma unroll
  for (int p = 0; p < 8; ++p){
    int n = p*8 + nl;
    *(us8*)(yb + (size_t)n*1024) = *(const us8*)&Wl[n][d8];
  }
}

// ---------------- residual 1: x1b(B,N,C) = bf16(xT + g1*a) ----------------
__global__ void k_resid1(const float* __restrict__ x, const bf16* __restrict__ Ab,
                         const float* __restrict__ g1, bf16* __restrict__ x1b){
  int b = blockIdx.z, c0 = blockIdx.y*64, n0 = blockIdx.x*64;
  __shared__ float t[64][65];
  int j = threadIdx.x & 63, i0 = (threadIdx.x >> 6)*16;
  const float* xp = x + ((size_t)b*1024 + c0)*1024 + n0;
  #pragma unroll
  for (int r = 0; r < 16; ++r)
    t[j][i0 + r] = xp[(size_t)(i0 + r)*1024 + j];
  __syncthreads();
  int i = threadIdx.x & 63, jj0 = (threadIdx.x >> 6)*16;
  float g = g1[c0 + i];
  #pragma unroll
  for (int r = 0; r < 16; ++r){
    size_t off = ((size_t)b*1024 + n0 + jj0 + r)*1024 + c0 + i;
    x1b[off] = f2b(t[jj0 + r][i] + g*b2f(Ab[off]));
  }
}

// ---------------- LN2 fused (row-contig, bf16 in) -> Y4 bf16 ----------------
__global__ void k_ln2(const bf16* __restrict__ x1b, const float* __restrict__ w,
                      const float* __restrict__ bias, bf16* __restrict__ y4){
  int row = blockIdx.x, t = threadIdx.x;
  ushort4 uv = *(const ushort4*)((const unsigned short*)x1b + (size_t)row*1024 + t*4);
  float vx = u2f(uv.x), vy = u2f(uv.y), vz = u2f(uv.z), vw = u2f(uv.w);
  float s = vx + vy + vz + vw;
  float q = vx*vx + vy*vy + vz*vz + vw*vw;
  #pragma unroll
  for (int d = 32; d >= 1; d >>= 1){ s += __shfl_xor(s, d); q += __shfl_xor(q, d); }
  __shared__ float ss[4], qq[4];
  int wv = t >> 6, ln = t & 63;
  if (ln == 0){ ss[wv] = s; qq[wv] = q; }
  __syncthreads();
  s = ss[0] + ss[1] + ss[2] + ss[3];
  q = qq[0] + qq[1] + qq[2] + qq[3];
  float m = s*(1.f/1024.f);
  float var = q*(1.f/1024.f) - m*m;
  float r = rsqrtf(var + 1e-5f);
  int c = t*4;
  ushort4 pk = make_ushort4(
      f2bu((vx - m)*r*w[c]   + bias[c]),
      f2bu((vy - m)*r*w[c+1] + bias[c+1]),
      f2bu((vz - m)*r*w[c+2] + bias[c+2]),
      f2bu((vw - m)*r*w[c+3] + bias[c+3]));
  *reinterpret_cast<ushort4*>(y4 + (size_t)row*1024 + c) = pk;
}

// ------- residual 2 (fallback path): out(B,C,N) = x1b + g2*m -------
__global__ void k_resid2(const bf16* __restrict__ x1b, const bf16* __restrict__ Mb,
                         const float* __restrict__ g2, float* __restrict__ out){
  int b = blockIdx.z, c0 = blockIdx.y*64, n0 = blockIdx.x*64;
  __shared__ float t[64][65];
  int i = threadIdx.x & 63, j0 = (threadIdx.x >> 6)*16;
  float g = g2[c0 + i];
  #pragma unroll
  for (int r = 0; r < 16; ++r){
    size_t off = ((size_t)b*1024 + n0 + j0 + r)*1024 + c0 + i;
    t[i][j0 + r] = b2f(x1b[off]) + g*b2f(Mb[off]);
  }
  __syncthreads();
  int j = threadIdx.x & 63, i0 = (threadIdx.x >> 6)*16;
  #pragma unroll
  for (int r = 0; r < 16; ++r)
    out[((size_t)b*1024 + c0 + i0 + r)*1024 + n0 + j] = t[i0 + r][j];
}

// ------- merged path: pure transpose, Mb already holds x1 + g2*m -------
__global__ void k_resid2t(const bf16* __restrict__ Mb, float* __restrict__ out){
  int b = blockIdx.z, c0 = blockIdx.y*64, n0 = blockIdx.x*64;
  __shared__ float t[64][65];
  int i = threadIdx.x & 63, j0 = (threadIdx.x >> 6)*16;
  #pragma unroll
  for (int r = 0; r < 16; ++r){
    size_t off = ((size_t)b*1024 + n0 + j0 + r)*1024 + c0 + i;
    t[i][j0 + r] = b2f(Mb[off]);
  }
  __syncthreads();
  int j = threadIdx.x & 63, i0 = (threadIdx.x >> 6)*16;
  #pragma unroll
  for (int r = 0; r < 16; ++r)
    out[((size_t)b*1024 + c0 + i0 + r)*1024 + n0 + j] = t[i0 + r][j];
}

extern "C" void kernel_launch(void* const* d_in, const int* in_sizes, int n_in,
                              void* d_out, int out_size, void* d_ws, size_t ws_size,
                              hipStream_t stream){
  (void)in_sizes; (void)n_in; (void)out_size;
  const float* x      = (const float*)d_in[0];
  const float* ln1_w  = (const float*)d_in[1];
  const float* ln1_b  = (const float*)d_in[2];
  const float* Wattn  = (const float*)d_in[3];
  const float* Wproj  = (const float*)d_in[4];
  const float* temp   = (const float*)d_in[5];
  const float* dbias  = (const float*)d_in[6];
  const float* ln2_w  = (const float*)d_in[7];
  const float* ln2_b  = (const float*)d_in[8];
  const float* W1     = (const float*)d_in[9];
  const float* b1     = (const float*)d_in[10];
  const float* W2     = (const float*)d_in[11];
  const float* b2     = (const float*)d_in[12];
  const float* g1     = (const float*)d_in[13];
  const float* g2     = (const float*)d_in[14];
  float* out = (float*)d_out;

  size_t off = 0;
  char* wsb = (char*)d_ws;
  auto alloc = [&](size_t bytes)->char*{
    char* p = wsb + off; off += (bytes + 255) & ~(size_t)255; return p;
  };
  // Wb/Yb placed LAST so [Wb|Yb|Hext] forms a contiguous 128 MB H when ws allows.
  bf16*  Y3  = (bf16*)alloc((size_t)16384*1024*2);   // also Y4 (LN2 out)
  bf16*  Mb  = (bf16*)alloc((size_t)16384*1024*2);   // MLP-down out (bf16)
  bf16*  Xb  = (bf16*)alloc((size_t)16384*1024*2);   // residual stream (bf16)
  bf16*  WAb = (bf16*)alloc((size_t)1024*1024*2);
  bf16*  WPb = (bf16*)alloc((size_t)1024*1024*2);
  bf16*  W1b = (bf16*)alloc((size_t)4096*1024*2);
  bf16*  W2b = (bf16*)alloc((size_t)4096*1024*2);
  float* mu  = (float*)alloc((size_t)16384*4);
  float* rs  = (float*)alloc((size_t)16384*4);
  float* S   = (float*)alloc((size_t)2048*128*4);
  float* tmp = (float*)alloc((size_t)16*8*1024*4);
  float* Pi  = (float*)alloc((size_t)16*8*1024*4);
  float* Pc  = (float*)alloc((size_t)16*8*1024*4);
  float* Ps  = (float*)alloc((size_t)16*64*1024*4);
  float* Pq  = (float*)alloc((size_t)16*64*1024*4);
  bf16*  Wb  = (bf16*)alloc((size_t)16384*1024*2);   // attn w; also Ab; H lo
  bf16*  Yb  = (bf16*)alloc((size_t)16384*1024*2);   // TSSA y; H mid
  // merged-H extension (64 MB) if workspace allows
  size_t rem = (ws_size > off) ? ws_size - off : 0;
  bool merged = rem >= ((size_t)16384*2048*2 + 4096);
  if (merged) (void)alloc((size_t)16384*2048*2);     // Hext right after Yb

  dim3 b256(256), b128(128), b512(512);

  // weights -> bf16 (single fused dispatch)
  k_f2b_all<<<dim3(10240), b256, 0, stream>>>(Wattn, Wproj, W1, W2,
                                              WAb, WPb, W1b, W2b);

  // LN1 stats (two-phase, coalesced)
  k_ln1_part<<<dim3(64, 16), b256, 0, stream>>>(x, Ps, Pq);
  k_ln1_finish<<<dim3(4, 16), b256, 0, stream>>>(Ps, Pq, mu, rs);
  k_ln1_apply<<<dim3(16, 16, 16), b256, 0, stream>>>(x, mu, rs, ln1_w, ln1_b, Y3);

  // c_attn
  k_gemm8<0><<<dim3(256), b512, 0, stream>>>(Y3, WAb, Wb, nullptr, nullptr, nullptr,
                                             1024, 1024, 1024, 1024, 4);

  // TSSA elementwise chain (vectorized)
  k_chunksum<false><<<dim3(2048), b128, 0, stream>>>(Wb, Pi, S);
  k_stageA<<<dim3(2048), b128, 0, stream>>>(Wb, S, temp, dbias, tmp);
  k_softmax_scan<<<dim3(128), b256, 0, stream>>>(tmp, Pi, Pc);
  k_chunksum<true><<<dim3(2048), b128, 0, stream>>>(Wb, Pi, S);
  k_stageC<<<dim3(2048), b128, 0, stream>>>(Wb, S, Pi, Pc, Yb);

  // c_proj (into Wb slab, now free)
  bf16* Ab = Wb;
  k_gemm8<0><<<dim3(256), b512, 0, stream>>>(Yb, WPb, Ab, nullptr, nullptr, nullptr,
                                             1024, 1024, 1024, 1024, 4);

  // residual 1
  k_resid1<<<dim3(16, 16, 16), b256, 0, stream>>>(x, Ab, g1, Xb);

  // LN2 -> Y4 (reuse Y3 slab)
  k_ln2<<<dim3(16384), b256, 0, stream>>>(Xb, ln2_w, ln2_b, Y3);

  if (merged){
    // Full H (16384 x 4096 bf16 = 128 MB) spans [Wb|Yb|Hext]
    bf16* H = Wb;
    // up: (16384,4096,1024) -> 64x16 = 1024 blocks, gelu
    k_gemm8<1><<<dim3(1024), b512, 0, stream>>>(Y3, W1b, H, b1, nullptr, nullptr,
                                                1024, 1024, 1024, 4096, 16);
    // down + fused residual-2 add: Mb = Xb + g2*(acc + b2)
    k_gemm8<4><<<dim3(256), b512, 0, stream>>>(H, W2b, Mb, b2, Xb, g2,
                                               4096, 4096, 4096, 1024, 4);
    // pure transpose to (B,C,H,W)
    k_resid2t<<<dim3(16, 16, 16), b256, 0, stream>>>(Mb, out);
  } else {
    // F-split fallback (2 x 2048); H-half overlays dead [Wb|Yb]
    bf16* Hb = Wb;
    for (int f = 0; f < 2; ++f){
      k_gemm8<1><<<dim3(512), b512, 0, stream>>>(Y3, W1b + (size_t)f*2048*1024, Hb,
                                                 b1 + f*2048, nullptr, nullptr,
                                                 1024, 1024, 1024, 2048, 8);
      if (f == 0)
        k_gemm8<0><<<dim3(256), b512, 0, stream>>>(Hb, W2b + f*2048, Mb, nullptr,
                                                   nullptr, nullptr,
                                                   2048, 2048, 4096, 1024, 4);
      else
        k_gemm8<3><<<dim3(256), b512, 0, stream>>>(Hb, W2b + f*2048, Mb, b2,
                                                   nullptr, nullptr,
                                                   2048, 2048, 4096, 1024, 4);
    }
    k_resid2<<<dim3(16, 16, 16), b256, 0, stream>>>(Xb, Mb, g2, out);
  }
}

// Round 17
// 530.956 us; speedup vs baseline: 1.0129x; 1.0129x over previous
//
#include <hip/hip_runtime.h>
#include <hip/hip_bf16.h>
#include <math.h>

using bf16 = __hip_bfloat16;
typedef __bf16 bf16x8 __attribute__((ext_vector_type(8)));
typedef float f32x4 __attribute__((ext_vector_type(4)));
typedef unsigned short us8 __attribute__((ext_vector_type(8)));

#define EPS16F 0.0009765625f

__device__ __forceinline__ float b2f(bf16 v){ return __bfloat162float(v); }
__device__ __forceinline__ bf16  f2b(float f){ return __float2bfloat16(f); }
__device__ __forceinline__ unsigned short f2bu(float f){
  bf16 h = __float2bfloat16(f); return __builtin_bit_cast(unsigned short, h);
}
__device__ __forceinline__ float u2f(unsigned short u){
  return b2f(__builtin_bit_cast(bf16, u));
}

__device__ __forceinline__ void gload16(const void* g, void* l){
  __builtin_amdgcn_global_load_lds((const __attribute__((address_space(1))) void*)g,
                                   (__attribute__((address_space(3))) void*)l, 16, 0, 0);
}

typedef const __attribute__((address_space(3))) char* lds_cp;

// LDS vector read with compile-time immediate offset (must be < 65536)
template<unsigned OFF>
__device__ __forceinline__ bf16x8 dsr(lds_cp p){
  static_assert(OFF < 65536u, "ds_read offset is 16-bit");
  bf16x8 d;
  asm volatile("ds_read_b128 %0, %1 offset:%c2"
               : "=v"(d) : "v"(p), "i"(OFF));
  return d;
}

// ---------------- fused fp32 -> bf16 convert for all 4 weights ----------------
__global__ void k_f2b_all(const float* __restrict__ w0, const float* __restrict__ w1,
                          const float* __restrict__ w2, const float* __restrict__ w3,
                          bf16* __restrict__ o0, bf16* __restrict__ o1,
                          bf16* __restrict__ o2, bf16* __restrict__ o3){
  // segments (elements): 1M, 1M, 4M, 4M
  long long i = (long long)(blockIdx.x*blockDim.x + threadIdx.x)*4;
  const float* in; bf16* out; long long off;
  if (i < 1048576){ in = w0; out = o0; off = i; }
  else if (i < 2097152){ in = w1; out = o1; off = i - 1048576; }
  else if (i < 6291456){ in = w2; out = o2; off = i - 2097152; }
  else { in = w3; out = o3; off = i - 6291456; }
  float4 v = *(const float4*)(in + off);
  ushort4 pk = make_ushort4(f2bu(v.x), f2bu(v.y), f2bu(v.z), f2bu(v.w));
  *reinterpret_cast<ushort4*>(out + off) = pk;
}

// ---------------- LN1 stats phase 1 ----------------
__global__ void __launch_bounds__(256) k_ln1_part(const float* __restrict__ x,
                                                  float* __restrict__ Ps,
                                                  float* __restrict__ Pq){
  int chunk = blockIdx.x, b = blockIdx.y;
  int t = threadIdx.x;
  const float4* xp = (const float4*)(x + ((size_t)b*1024 + chunk*16)*1024) + t;
  float4 s = {0.f,0.f,0.f,0.f}, q = {0.f,0.f,0.f,0.f};
  #pragma unroll
  for (int c = 0; c < 16; ++c){
    float4 v = xp[c*256];
    s.x += v.x; s.y += v.y; s.z += v.z; s.w += v.w;
    q.x += v.x*v.x; q.y += v.y*v.y; q.z += v.z*v.z; q.w += v.w*v.w;
  }
  size_t o = ((size_t)(b*64 + chunk))*256 + t;
  ((float4*)Ps)[o] = s;
  ((float4*)Pq)[o] = q;
}

// ---------------- LN1 stats phase 2 ----------------
__global__ void __launch_bounds__(256) k_ln1_finish(const float* __restrict__ Ps,
                                                    const float* __restrict__ Pq,
                                                    float* __restrict__ mu,
                                                    float* __restrict__ rs){
  int nb = blockIdx.x, b = blockIdx.y;
  int n = nb*256 + threadIdx.x;
  const float* ps = Ps + (size_t)b*64*1024 + n;
  const float* pq = Pq + (size_t)b*64*1024 + n;
  float S = 0.f, Q = 0.f;
  #pragma unroll 8
  for (int c = 0; c < 64; ++c){ S += ps[(size_t)c*1024]; Q += pq[(size_t)c*1024]; }
  float m = S*(1.f/1024.f);
  float var = Q*(1.f/1024.f) - m*m;
  mu[b*1024 + n] = m;
  rs[b*1024 + n] = rsqrtf(var + 1e-5f);
}

// ---------------- LN1 apply + transpose ----------------
__global__ void k_ln1_apply(const float* __restrict__ x, const float* __restrict__ mu,
                            const float* __restrict__ rs, const float* __restrict__ w,
                            const float* __restrict__ bias, bf16* __restrict__ y3){
  int b = blockIdx.z, c0 = blockIdx.y*64, n0 = blockIdx.x*64;
  __shared__ float t[64][65];
  int j = threadIdx.x & 63, i0 = (threadIdx.x >> 6)*16;
  const float* xp = x + ((size_t)b*1024 + c0)*1024 + n0;
  #pragma unroll
  for (int r = 0; r < 16; ++r)
    t[j][i0 + r] = xp[(size_t)(i0 + r)*1024 + j];
  __syncthreads();
  int i = threadIdx.x & 63, jj0 = (threadIdx.x >> 6)*16;
  float wc = w[c0 + i], bc = bias[c0 + i];
  bf16* yp = y3 + ((size_t)b*1024 + n0)*1024 + c0 + i;
  #pragma unroll
  for (int r = 0; r < 16; ++r){
    int n = n0 + jj0 + r;
    float v = t[jj0 + r][i];
    yp[(size_t)(jj0 + r)*1024] = f2b((v - mu[b*1024 + n])*rs[b*1024 + n]*wc + bc);
  }
}

// ================= 256x256 8-phase GEMM (R7 best-measured) =================
// EPI: 0 plain, 1 +bias+fast-gelu, 2 +bias, 3 +bias+accumulate-into-out
#define PH(PA, PB, JO, MH, VM, STAGE_STMT)                                     \
  {                                                                            \
    if ((MH) == 0){                                                            \
      b[0] = dsr<(JO) +    0>(PB); b[1] = dsr<(JO) + 1024>(PB);                \
      b[2] = dsr<(JO) + 2048>(PB); b[3] = dsr<(JO) + 3072>(PB);                \
    }                                                                          \
    a[0] = dsr<(JO) + (MH)*4096u +    0>(PA);                                  \
    a[1] = dsr<(JO) + (MH)*4096u + 1024>(PA);                                  \
    a[2] = dsr<(JO) + (MH)*4096u + 2048>(PA);                                  \
    a[3] = dsr<(JO) + (MH)*4096u + 3072>(PA);                                  \
    STAGE_STMT;                                                                \
    if (VM) asm volatile("s_waitcnt vmcnt(4)" ::: "memory");                   \
    __builtin_amdgcn_s_barrier();                                              \
    asm volatile("s_waitcnt lgkmcnt(0)" ::: "memory");                         \
    __builtin_amdgcn_sched_barrier(0);                                         \
    __builtin_amdgcn_s_setprio(1);                                             \
    _Pragma("unroll")                                                          \
    for (int i_ = 0; i_ < 4; ++i_)                                             \
      _Pragma("unroll")                                                        \
      for (int n_ = 0; n_ < 4; ++n_)                                           \
        acc[(MH)*4 + i_][n_] = __builtin_amdgcn_mfma_f32_16x16x32_bf16(        \
            a[i_], b[n_], acc[(MH)*4 + i_][n_], 0, 0, 0);                      \
    __builtin_amdgcn_s_setprio(0);                                             \
    __builtin_amdgcn_s_barrier();                                              \
  }

#define STAGE_A(KB, SLOT)                                                      \
  { const char* g_ = Ag + (size_t)(KB)*2;                                      \
    gload16(g_,        smem + (SLOT)*32768 + t*16);                            \
    gload16(g_ + a128, smem + (SLOT)*32768 + 8192 + t*16); }
#define STAGE_B(KB, SLOT)                                                      \
  { const char* g_ = Wg + (size_t)(KB)*2;                                      \
    gload16(g_,        smem + (SLOT)*32768 + 16384 + t*16);                    \
    gload16(g_ + w128, smem + (SLOT)*32768 + 16384 + 8192 + t*16); }

template<int EPI>
__global__ void __launch_bounds__(512, 2) k_gemm8(const bf16* __restrict__ A,
                                                  const bf16* __restrict__ W,
                                                  bf16* __restrict__ out,
                                                  const float* __restrict__ bias,
                                                  int K, int lda, int ldw, int ldo,
                                                  int nbx){
  __shared__ __align__(16) char smem[131072];
  int nwg = gridDim.x;
  int cpx = nwg >> 3;
  int bid = blockIdx.x;
  int swz = (bid & 7)*cpx + (bid >> 3);
  int bx = swz % nbx, by = swz / nbx;
  int m0 = by*256, n0 = bx*256;
  int t = threadIdx.x;
  int lane = t & 63, wave = t >> 6;
  int wr = wave >> 2, wc = wave & 3;     // 2x4 waves; each owns 128x64
  int lr = lane & 15, lg = lane >> 4;
  unsigned cswz = (unsigned)((lg ^ ((lr >> 1) & 3))*16);
  int srow = t >> 2;
  int sg = (t & 3) ^ ((t >> 3) & 3);
  f32x4 acc[8][4] = {};
  bf16x8 a[4], b[4];
  int nt = K >> 6;                        // even (K = 1024/2048/4096)

  const char* Ag = (const char*)A + ((size_t)(m0 + srow)*lda + sg*8)*2;
  const char* Wg = (const char*)W + ((size_t)(n0 + srow)*ldw + sg*8)*2;
  const size_t a128 = (size_t)lda*256;    // +128 rows, bytes
  const size_t w128 = (size_t)ldw*256;
  lds_cp pa0 = (lds_cp)(smem + (wr*128 + lr)*64 + cswz);
  lds_cp pb0 = (lds_cp)(smem + 16384 + (wc*64 + lr)*64 + cswz);
  lds_cp pa1 = pa0 + 65536;
  lds_cp pb1 = pb0 + 65536;

  STAGE_A(0, 0)  STAGE_B(0, 0)
  STAGE_A(32, 1) STAGE_B(32, 1)
  asm volatile("s_waitcnt vmcnt(4)" ::: "memory");
  __builtin_amdgcn_s_barrier();

  int nh = nt >> 1;
  for (int tp = 0; tp < nh; ++tp){
    int tt = tp*2;
    int kn  = (tt + 1)*64;
    int kn2 = (tt + 2 < nt) ? (tt + 2)*64 : 0;
    PH(pa0, pb0, 0u,     0, 0, STAGE_A(kn, 2))
    PH(pa0, pb0, 0u,     1, 1, STAGE_B(kn, 2))
    PH(pa0, pb0, 32768u, 0, 0, STAGE_A(kn + 32, 3))
    PH(pa0, pb0, 32768u, 1, 1, STAGE_B(kn + 32, 3))
    PH(pa1, pb1, 0u,     0, 0, STAGE_A(kn2, 0))
    PH(pa1, pb1, 0u,     1, 1, STAGE_B(kn2, 0))
    PH(pa1, pb1, 32768u, 0, 0, STAGE_A(kn2 + 32, 1))
    PH(pa1, pb1, 32768u, 1, 1, STAGE_B(kn2 + 32, 1))
  }

  #pragma unroll
  for (int m = 0; m < 8; ++m){
    #pragma unroll
    for (int n = 0; n < 4; ++n){
      int col = n0 + wc*64 + n*16 + lr;
      #pragma unroll
      for (int j = 0; j < 4; ++j){
        int row = m0 + wr*128 + m*16 + lg*4 + j;
        size_t idx = (size_t)row*ldo + col;
        float v = acc[m][n][j];
        if (EPI >= 1) v += bias[col];
        if (EPI == 1) v = v / (1.f + __expf(-1.702f*v));   // fast gelu
        if (EPI == 3) v += b2f(out[idx]);
        out[idx] = f2b(v);
      }
    }
  }
}

// ---------- TSSA chain: vectorized (bf16x8 staged) versions ----------
template<bool WEIGHTED>
__global__ void __launch_bounds__(128) k_chunksum(const bf16* __restrict__ Wb,
                                                  const float* __restrict__ Pi,
                                                  float* __restrict__ S){
  int blk = blockIdx.x;
  int ch = blk & 15, h = (blk >> 4) & 7, b = blk >> 7;
  int t = threadIdx.x;
  int nl = t >> 4, d8 = (t & 15)*8;
  const bf16* gb = Wb + ((size_t)(b*1024 + ch*64))*1024 + h*128 + d8;
  const float* pip = Pi + (size_t)(b*8 + h)*1024 + ch*64;
  float acc[8] = {};
  #pragma unroll
  for (int p = 0; p < 8; ++p){
    int n = p*8 + nl;
    us8 v = *(const us8*)(gb + (size_t)n*1024);
    float pi = WEIGHTED ? pip[n] : 1.f;
    #pragma unroll
    for (int j = 0; j < 8; ++j){
      float w = u2f(v[j]);
      acc[j] += w*w*pi;
    }
  }
  __shared__ float Sp[8][128];
  #pragma unroll
  for (int j = 0; j < 8; ++j) Sp[nl][d8 + j] = acc[j];
  __syncthreads();
  float s = 0.f;
  #pragma unroll
  for (int g = 0; g < 8; ++g) s += Sp[g][t];
  S[(size_t)blk*128 + t] = s;
}

__global__ void __launch_bounds__(128) k_stageA(const bf16* __restrict__ Wb,
                                                const float* __restrict__ S1,
                                                const float* __restrict__ temp,
                                                const float* __restrict__ dbias,
                                                float* __restrict__ tmp){
  int blk = blockIdx.x;
  int ch = blk & 15, h = (blk >> 4) & 7, b = blk >> 7;
  int t = threadIdx.x;
  __shared__ __align__(16) unsigned short Wl[64][136];
  __shared__ float V[64][129];
  int nl = t >> 4, d8 = (t & 15)*8;
  const bf16* gb = Wb + ((size_t)(b*1024 + ch*64))*1024 + h*128 + d8;
  #pragma unroll
  for (int p = 0; p < 8; ++p){
    int n = p*8 + nl;
    *(us8*)&Wl[n][d8] = *(const us8*)(gb + (size_t)n*1024);
  }
  const float* sp = S1 + (size_t)(b*8 + h)*16*128 + t;
  float base = 0.f;
  for (int c = 0; c < ch; ++c) base += sp[(size_t)c*128];
  __syncthreads();
  float run = base;                        // t = d
  for (int n = 0; n < 64; ++n){
    float w = u2f(Wl[n][t]);
    float sq = w*w;
    run += sq;
    V[n][t] = sq / fmaxf(run, EPS16F);
  }
  __syncthreads();
  int n_loc = t >> 1, half = t & 1;
  float s = 0.f;
  for (int k = 0; k < 64; ++k) s += V[n_loc][half*64 + k];
  s += __shfl_xor(s, 1);
  if (half == 0){
    int n = ch*64 + n_loc;
    float db = dbias[h*1024 + n];
    tmp[(size_t)(b*8 + h)*1024 + n] = (s + 128.f*db)*temp[h];
  }
}

__global__ void k_softmax_scan(const float* __restrict__ tmp, float* __restrict__ Pi,
                               float* __restrict__ Pc){
  int bh = blockIdx.x; int b = bh >> 3, h = bh & 7;
  int t = threadIdx.x;
  const float* tp = tmp + (size_t)b*8*1024;
  float p[4];
  #pragma unroll
  for (int i = 0; i < 4; ++i){
    int n = t*4 + i;
    float v[8]; float mx = -1e30f;
    #pragma unroll
    for (int hh = 0; hh < 8; ++hh){ v[hh] = tp[hh*1024 + n]; mx = fmaxf(mx, v[hh]); }
    float Z = 0.f;
    #pragma unroll
    for (int hh = 0; hh < 8; ++hh) Z += expf(v[hh] - mx);
    p[i] = expf(v[h] - mx)/Z;
    Pi[(size_t)bh*1024 + n] = p[i];
  }
  float l0 = p[0], l1 = l0 + p[1], l2 = l1 + p[2], l3 = l2 + p[3];
  float ts = l3, sc = ts;
  int ln = t & 63, wv = t >> 6;
  #pragma unroll
  for (int d = 1; d < 64; d <<= 1){
    float o = __shfl_up(sc, d);
    if (ln >= d) sc += o;
  }
  __shared__ float wsum[4];
  if (ln == 63) wsum[wv] = sc;
  __syncthreads();
  float woff = 0.f;
  for (int w2 = 0; w2 < 4; ++w2) if (w2 < wv) woff += wsum[w2];
  float excl = woff + sc - ts;
  size_t o4 = (size_t)bh*1024 + t*4;
  Pc[o4]   = excl + l0;
  Pc[o4+1] = excl + l1;
  Pc[o4+2] = excl + l2;
  Pc[o4+3] = excl + l3;
}

__global__ void __launch_bounds__(128) k_stageC(const bf16* __restrict__ Wb,
                                                const float* __restrict__ S2,
                                                const float* __restrict__ Pi,
                                                const float* __restrict__ Pc,
                                                bf16* __restrict__ Y){
  int blk = blockIdx.x;
  int ch = blk & 15, h = (blk >> 4) & 7, b = blk >> 7;
  int t = threadIdx.x;
  __shared__ __align__(16) unsigned short Wl[64][136];
  int nl = t >> 4, d8 = (t & 15)*8;
  const bf16* gb = Wb + ((size_t)(b*1024 + ch*64))*1024 + h*128 + d8;
  #pragma unroll
  for (int p = 0; p < 8; ++p){
    int n = p*8 + nl;
    *(us8*)&Wl[n][d8] = *(const us8*)(gb + (size_t)n*1024);
  }
  const float* sp = S2 + (size_t)(b*8 + h)*16*128 + t;
  float base = 0.f;
  for (int c = 0; c < ch; ++c) base += sp[(size_t)c*128];
  const float* pip = Pi + (size_t)(b*8 + h)*1024 + ch*64;
  const float* pcp = Pc + (size_t)(b*8 + h)*1024 + ch*64;
  __syncthreads();
  float run = base;                        // t = d
  for (int n = 0; n < 64; ++n){
    float w = u2f(Wl[n][t]);
    float sq = w*w;
    float pi = pip[n];
    run += sq*pi;
    float dots = run / (pcp[n] + EPS16F);
    float at = 1.0f/(1.0f + dots);
    Wl[n][t] = f2bu(-(w*pi)*at);           // column-exclusive overwrite
  }
  __syncthreads();
  bf16* yb = Y + ((size_t)(b*1024 + ch*64))*1024 + h*128 + d8;
  #pragma unroll
  for (int p = 0; p < 8; ++p){
    int n = p*8 + nl;
    *(us8*)(yb + (size_t)n*1024) = *(const us8*)&Wl[n][d8];
  }
}

// ---------------- residual 1: x1b(B,N,C) = bf16(xT + g1*a) ----------------
__global__ void k_resid1(const float* __restrict__ x, const bf16* __restrict__ Ab,
                         const float* __restrict__ g1, bf16* __restrict__ x1b){
  int b = blockIdx.z, c0 = blockIdx.y*64, n0 = blockIdx.x*64;
  __shared__ float t[64][65];
  int j = threadIdx.x & 63, i0 = (threadIdx.x >> 6)*16;
  const float* xp = x + ((size_t)b*1024 + c0)*1024 + n0;
  #pragma unroll
  for (int r = 0; r < 16; ++r)
    t[j][i0 + r] = xp[(size_t)(i0 + r)*1024 + j];
  __syncthreads();
  int i = threadIdx.x & 63, jj0 = (threadIdx.x >> 6)*16;
  float g = g1[c0 + i];
  #pragma unroll
  for (int r = 0; r < 16; ++r){
    size_t off = ((size_t)b*1024 + n0 + jj0 + r)*1024 + c0 + i;
    x1b[off] = f2b(t[jj0 + r][i] + g*b2f(Ab[off]));
  }
}

// ---------------- LN2 fused (row-contig, bf16 in) -> Y4 bf16 ----------------
__global__ void k_ln2(const bf16* __restrict__ x1b, const float* __restrict__ w,
                      const float* __restrict__ bias, bf16* __restrict__ y4){
  int row = blockIdx.x, t = threadIdx.x;
  ushort4 uv = *(const ushort4*)((const unsigned short*)x1b + (size_t)row*1024 + t*4);
  float vx = u2f(uv.x), vy = u2f(uv.y), vz = u2f(uv.z), vw = u2f(uv.w);
  float s = vx + vy + vz + vw;
  float q = vx*vx + vy*vy + vz*vz + vw*vw;
  #pragma unroll
  for (int d = 32; d >= 1; d >>= 1){ s += __shfl_xor(s, d); q += __shfl_xor(q, d); }
  __shared__ float ss[4], qq[4];
  int wv = t >> 6, ln = t & 63;
  if (ln == 0){ ss[wv] = s; qq[wv] = q; }
  __syncthreads();
  s = ss[0] + ss[1] + ss[2] + ss[3];
  q = qq[0] + qq[1] + qq[2] + qq[3];
  float m = s*(1.f/1024.f);
  float var = q*(1.f/1024.f) - m*m;
  float r = rsqrtf(var + 1e-5f);
  int c = t*4;
  ushort4 pk = make_ushort4(
      f2bu((vx - m)*r*w[c]   + bias[c]),
      f2bu((vy - m)*r*w[c+1] + bias[c+1]),
      f2bu((vz - m)*r*w[c+2] + bias[c+2]),
      f2bu((vw - m)*r*w[c+3] + bias[c+3]));
  *reinterpret_cast<ushort4*>(y4 + (size_t)row*1024 + c) = pk;
}

// ---------------- residual 2 + transpose: out(B,C,N) = x1b + g2*m ----------------
__global__ void k_resid2(const bf16* __restrict__ x1b, const bf16* __restrict__ Mb,
                         const float* __restrict__ g2, float* __restrict__ out){
  int b = blockIdx.z, c0 = blockIdx.y*64, n0 = blockIdx.x*64;
  __shared__ float t[64][65];
  int i = threadIdx.x & 63, j0 = (threadIdx.x >> 6)*16;
  float g = g2[c0 + i];
  #pragma unroll
  for (int r = 0; r < 16; ++r){
    size_t off = ((size_t)b*1024 + n0 + j0 + r)*1024 + c0 + i;
    t[i][j0 + r] = b2f(x1b[off]) + g*b2f(Mb[off]);
  }
  __syncthreads();
  int j = threadIdx.x & 63, i0 = (threadIdx.x >> 6)*16;
  #pragma unroll
  for (int r = 0; r < 16; ++r)
    out[((size_t)b*1024 + c0 + i0 + r)*1024 + n0 + j] = t[i0 + r][j];
}

extern "C" void kernel_launch(void* const* d_in, const int* in_sizes, int n_in,
                              void* d_out, int out_size, void* d_ws, size_t ws_size,
                              hipStream_t stream){
  (void)in_sizes; (void)n_in; (void)out_size;
  const float* x      = (const float*)d_in[0];
  const float* ln1_w  = (const float*)d_in[1];
  const float* ln1_b  = (const float*)d_in[2];
  const float* Wattn  = (const float*)d_in[3];
  const float* Wproj  = (const float*)d_in[4];
  const float* temp   = (const float*)d_in[5];
  const float* dbias  = (const float*)d_in[6];
  const float* ln2_w  = (const float*)d_in[7];
  const float* ln2_b  = (const float*)d_in[8];
  const float* W1     = (const float*)d_in[9];
  const float* b1     = (const float*)d_in[10];
  const float* W2     = (const float*)d_in[11];
  const float* b2     = (const float*)d_in[12];
  const float* g1     = (const float*)d_in[13];
  const float* g2     = (const float*)d_in[14];
  float* out = (float*)d_out;

  size_t off = 0;
  char* wsb = (char*)d_ws;
  auto alloc = [&](size_t bytes)->char*{
    char* p = wsb + off; off += (bytes + 255) & ~(size_t)255; return p;
  };
  // Wb/Yb placed LAST so [Wb|Yb|Hext] forms a contiguous 128 MB H when ws allows.
  bf16*  Y3  = (bf16*)alloc((size_t)16384*1024*2);   // also Y4 (LN2 out)
  bf16*  Mb  = (bf16*)alloc((size_t)16384*1024*2);   // MLP-down out (bf16)
  bf16*  Xb  = (bf16*)alloc((size_t)16384*1024*2);   // residual stream (bf16)
  bf16*  WAb = (bf16*)alloc((size_t)1024*1024*2);
  bf16*  WPb = (bf16*)alloc((size_t)1024*1024*2);
  bf16*  W1b = (bf16*)alloc((size_t)4096*1024*2);
  bf16*  W2b = (bf16*)alloc((size_t)4096*1024*2);
  float* mu  = (float*)alloc((size_t)16384*4);
  float* rs  = (float*)alloc((size_t)16384*4);
  float* S   = (float*)alloc((size_t)2048*128*4);
  float* tmp = (float*)alloc((size_t)16*8*1024*4);
  float* Pi  = (float*)alloc((size_t)16*8*1024*4);
  float* Pc  = (float*)alloc((size_t)16*8*1024*4);
  float* Ps  = (float*)alloc((size_t)16*64*1024*4);
  float* Pq  = (float*)alloc((size_t)16*64*1024*4);
  bf16*  Wb  = (bf16*)alloc((size_t)16384*1024*2);   // attn w; also Ab; H lo
  bf16*  Yb  = (bf16*)alloc((size_t)16384*1024*2);   // TSSA y; H mid
  // merged-H extension (64 MB) if workspace allows
  size_t rem = (ws_size > off) ? ws_size - off : 0;
  bool merged = rem >= ((size_t)16384*2048*2 + 4096);
  if (merged) (void)alloc((size_t)16384*2048*2);     // Hext right after Yb

  dim3 b256(256), b128(128), b512(512);

  // weights -> bf16 (single fused dispatch)
  k_f2b_all<<<dim3(10240), b256, 0, stream>>>(Wattn, Wproj, W1, W2,
                                              WAb, WPb, W1b, W2b);

  // LN1 stats (two-phase, coalesced)
  k_ln1_part<<<dim3(64, 16), b256, 0, stream>>>(x, Ps, Pq);
  k_ln1_finish<<<dim3(4, 16), b256, 0, stream>>>(Ps, Pq, mu, rs);
  k_ln1_apply<<<dim3(16, 16, 16), b256, 0, stream>>>(x, mu, rs, ln1_w, ln1_b, Y3);

  // c_attn
  k_gemm8<0><<<dim3(256), b512, 0, stream>>>(Y3, WAb, Wb, nullptr,
                                             1024, 1024, 1024, 1024, 4);

  // TSSA elementwise chain (vectorized)
  k_chunksum<false><<<dim3(2048), b128, 0, stream>>>(Wb, Pi, S);
  k_stageA<<<dim3(2048), b128, 0, stream>>>(Wb, S, temp, dbias, tmp);
  k_softmax_scan<<<dim3(128), b256, 0, stream>>>(tmp, Pi, Pc);
  k_chunksum<true><<<dim3(2048), b128, 0, stream>>>(Wb, Pi, S);
  k_stageC<<<dim3(2048), b128, 0, stream>>>(Wb, S, Pi, Pc, Yb);

  // c_proj (into Wb slab, now free)
  bf16* Ab = Wb;
  k_gemm8<0><<<dim3(256), b512, 0, stream>>>(Yb, WPb, Ab, nullptr,
                                             1024, 1024, 1024, 1024, 4);

  // residual 1
  k_resid1<<<dim3(16, 16, 16), b256, 0, stream>>>(x, Ab, g1, Xb);

  // LN2 -> Y4 (reuse Y3 slab)
  k_ln2<<<dim3(16384), b256, 0, stream>>>(Xb, ln2_w, ln2_b, Y3);

  if (merged){
    // Full H (16384 x 4096 bf16 = 128 MB) spans [Wb|Yb|Hext]
    bf16* H = Wb;
    // up: (16384,4096,1024) -> 64x16 = 1024 blocks, gelu
    k_gemm8<1><<<dim3(1024), b512, 0, stream>>>(Y3, W1b, H, b1,
                                                1024, 1024, 1024, 4096, 16);
    // down: (16384,1024,4096) -> 256 blocks, bias only
    k_gemm8<2><<<dim3(256), b512, 0, stream>>>(H, W2b, Mb, b2,
                                               4096, 4096, 4096, 1024, 4);
  } else {
    // F-split fallback (2 x 2048); H-half overlays dead [Wb|Yb]
    bf16* Hb = Wb;
    for (int f = 0; f < 2; ++f){
      k_gemm8<1><<<dim3(512), b512, 0, stream>>>(Y3, W1b + (size_t)f*2048*1024, Hb,
                                                 b1 + f*2048, 1024, 1024, 1024, 2048, 8);
      if (f == 0)
        k_gemm8<0><<<dim3(256), b512, 0, stream>>>(Hb, W2b + f*2048, Mb, nullptr,
                                                   2048, 2048, 4096, 1024, 4);
      else
        k_gemm8<3><<<dim3(256), b512, 0, stream>>>(Hb, W2b + f*2048, Mb, b2,
                                                   2048, 2048, 4096, 1024, 4);
    }
  }

  // residual 2 + transpose to (B,C,H,W)
  k_resid2<<<dim3(16, 16, 16), b256, 0, stream>>>(Xb, Mb, g2, out);
}